// Round 11
// baseline (190.812 us; speedup 1.0000x reference)
//
#include <hip/hip_runtime.h>
#include <hip/hip_bf16.h>
#include <math.h>

#define NBOX   16384
#define NPRE   1024
#define NPOST  512
#define NMS_TH 0.8f
#define DEN_EPS 1e-8f
#define GPB    16              // blocks per batch in k_mega
#define NB2    4096            // 12-bit histogram buckets
#define SCAP   2048            // sorted-candidate LDS cap
#define CPAIR  1024            // per-block dense pair list cap
#define SEGCAP 65536           // per-block hit segment (worst 64*1023=65472)

typedef unsigned long long ull;

__device__ __forceinline__ unsigned mono_f32(float a) {
  unsigned u = __float_as_uint(a);
  return (u & 0x80000000u) ? ~u : (u | 0x80000000u);
}

// ---------------------------------------------------------------------
// exact rotated IoU > thresh from packed geometry.
// p* = (x, y, rad, area); g* = (dx, dy, cos, sin).
// Corner expressions identical to the verified binfo version (bitwise).
// Stable argsort by (angle,idx) == successor chain on key=(mono(ang)<<5)|idx.
// ---------------------------------------------------------------------
__device__ bool iou_geom_gt(float4 pa, float4 ga, float4 pb, float4 gb) {
  const float offx[4] = {0.5f, -0.5f, -0.5f, 0.5f};
  const float offy[4] = {0.5f, 0.5f, -0.5f, -0.5f};
  float ax = pa.x, ay = pa.y, bx = pb.x, by = pb.y;
  float aA = pa.w, aB = pb.w;
  float cA = ga.z, sA = ga.w, cB = gb.z, sB = gb.w;
  float acx[4], acy[4], bcx[4], bcy[4];
#pragma unroll
  for (int k = 0; k < 4; ++k) {
    float lx = ga.x * offx[k], ly = ga.y * offy[k];
    acx[k] = ax + lx * cA - ly * sA;
    acy[k] = ay + lx * sA + ly * cA;
    float mx2 = gb.x * offx[k], my2 = gb.y * offy[k];
    bcx[k] = bx + mx2 * cB - my2 * sB;
    bcy[k] = by + mx2 * sB + my2 * cB;
  }
  float px[24], py[24];
  bool act[24];
#pragma unroll
  for (int p = 0; p < 4; ++p) {
    float A0x = acx[p], A0y = acy[p];
    float DAx = acx[(p + 1) & 3] - A0x, DAy = acy[(p + 1) & 3] - A0y;
#pragma unroll
    for (int q = 0; q < 4; ++q) {
      float B0x = bcx[q], B0y = bcy[q];
      float DBx = bcx[(q + 1) & 3] - B0x, DBy = bcy[(q + 1) & 3] - B0y;
      float den = DAx * DBy - DAy * DBx;
      float dxx = B0x - A0x, dyy = B0y - A0y;
      bool dok = fabsf(den) > DEN_EPS;
      float dens = dok ? den : 1.0f;
      float t = (dxx * DBy - dyy * DBx) / dens;
      float u = (dxx * DAy - dyy * DAx) / dens;
      int k = p * 4 + q;
      px[k] = A0x + t * DAx;
      py[k] = A0y + t * DAy;
      act[k] = dok && t >= 0.f && t <= 1.f && u >= 0.f && u <= 1.f;
    }
  }
#pragma unroll
  for (int k = 0; k < 4; ++k) {        // corners of A in B
    float rx = acx[k] - bx, ry = acy[k] - by;
    float qx =  rx * cB + ry * sB, qy = -rx * sB + ry * cB;
    px[16 + k] = acx[k]; py[16 + k] = acy[k];
    act[16 + k] = (fabsf(qx) <= gb.x * 0.5f + 1e-5f) && (fabsf(qy) <= gb.y * 0.5f + 1e-5f);
  }
#pragma unroll
  for (int k = 0; k < 4; ++k) {        // corners of B in A
    float rx = bcx[k] - ax, ry = bcy[k] - ay;
    float qx =  rx * cA + ry * sA, qy = -rx * sA + ry * cA;
    px[20 + k] = bcx[k]; py[20 + k] = bcy[k];
    act[20 + k] = (fabsf(qx) <= ga.x * 0.5f + 1e-5f) && (fabsf(qy) <= ga.y * 0.5f + 1e-5f);
  }
  int cnt = 0; float sx = 0.f, sy = 0.f;
#pragma unroll
  for (int k = 0; k < 24; ++k)
    if (act[k]) { cnt++; sx += px[k]; sy += py[k]; }
  float fc = (float)(cnt > 1 ? cnt : 1);
  float cx0 = sx / fc, cy0 = sy / fc;
  ull key[24];
#pragma unroll
  for (int k = 0; k < 24; ++k) {
    float ang = atan2f(py[k] - cy0, px[k] - cx0);
    key[k] = act[k] ? ((((ull)mono_f32(ang)) << 5) | (ull)k) : ~0ull;
  }
  ull kmin = ~0ull; float fx = 0.f, fy = 0.f;
#pragma unroll
  for (int k = 0; k < 24; ++k) {
    bool lt = key[k] < kmin;
    kmin = lt ? key[k] : kmin;
    fx = lt ? px[k] : fx;
    fy = lt ? py[k] : fy;
  }
  float ssum = 0.f;
#pragma unroll
  for (int k = 0; k < 24; ++k) {
    ull myk = key[k];
    ull best = ~0ull; float nx = fx, ny = fy;    // default: wrap to first
#pragma unroll
    for (int j = 0; j < 24; ++j) {
      bool c = (key[j] > myk) && (key[j] < best);
      best = c ? key[j] : best;
      nx = c ? px[j] : nx;
      ny = c ? py[j] : ny;
    }
    float contrib = px[k] * ny - py[k] * nx;
    ssum += (myk != ~0ull) ? contrib : 0.f;
  }
  float inter = 0.5f * fabsf(ssum);
  float uni = aA + aB - inter;
  return inter / fmaxf(uni, 1e-6f) > NMS_TH;
}

// =====================================================================
// K1 mega: grid = B*GPB, 256 thr. Fully redundant per block:
// keys -> LDS hist -> in-place suffix -> threshold -> bucket-sorted
// compaction -> histogram-based exact rank -> geometry (LDS) ->
// cheap sweep (own rows) -> dense exact IoU -> per-block hit segment.
// =====================================================================
__global__ __launch_bounds__(256) void k_mega(
    const float* __restrict__ box, const float* __restrict__ cls,
    int* __restrict__ topi, unsigned* __restrict__ hitseg,
    unsigned* __restrict__ hitcnt) {
  __shared__ unsigned sufx[NB2];       // 16 KB: hist -> suffix (in place)
  __shared__ ull scand[SCAP];          // 16 KB: sorted candidates; then geomL
  __shared__ unsigned tiec[NB2];       // 16 KB: tie counters; then pinfoL
  __shared__ unsigned rankIdx[NPRE];   // 4 KB: rank -> box idx; then candPk
  __shared__ unsigned wtot[4];
  __shared__ unsigned thrT, cntP, cntH;
  float4* geomL  = (float4*)scand;     // alias after rank phase
  float4* pinfoL = (float4*)tiec;      // alias after rank phase
  unsigned* candPk = rankIdx;          // alias after geometry phase

  const int b = blockIdx.x >> 4, blk = blockIdx.x & (GPB - 1);
  const int t = threadIdx.x;
  const int lane = t & 63, wv = t >> 6;

  // ---- P0: zero ----
#pragma unroll
  for (int k = 0; k < NB2 / 256; ++k) { sufx[t + k * 256] = 0u; tiec[t + k * 256] = 0u; }
  if (t == 0) { cntP = 0u; cntH = 0u; }
  __syncthreads();

  // ---- P1: histogram (float4 x3 -> 4 boxes per iter) ----
  const float4* cb4 = (const float4*)(cls + (size_t)b * NBOX * 3);
  for (int k = 0; k < 16; ++k) {
    int base4 = k * 768 + 3 * t;
    float4 A = cb4[base4], Bq = cb4[base4 + 1], Cq = cb4[base4 + 2];
    float s0 = fmaxf(A.x, fmaxf(A.y, A.z));
    float s1 = fmaxf(A.w, fmaxf(Bq.x, Bq.y));
    float s2 = fmaxf(Bq.z, fmaxf(Bq.w, Cq.x));
    float s3 = fmaxf(Cq.y, fmaxf(Cq.z, Cq.w));
    atomicAdd(&sufx[mono_f32(s0) >> 20], 1u);
    atomicAdd(&sufx[mono_f32(s1) >> 20], 1u);
    atomicAdd(&sufx[mono_f32(s2) >> 20], 1u);
    atomicAdd(&sufx[mono_f32(s3) >> 20], 1u);
  }
  __syncthreads();

  // ---- P2: in-place suffix sum + threshold bucket T ----
  unsigned hloc[16], csum = 0;
#pragma unroll
  for (int k = 0; k < 16; ++k) { hloc[k] = sufx[t * 16 + k]; csum += hloc[k]; }
  unsigned v = csum;
#pragma unroll
  for (int off = 1; off < 64; off <<= 1) {
    unsigned o = __shfl_down((int)v, off, 64);
    if (lane + off < 64) v += o;
  }
  if (lane == 0) wtot[wv] = v;
  __syncthreads();
  unsigned shi = 0;
  for (int w2 = wv + 1; w2 < 4; ++w2) shi += wtot[w2];
  unsigned run = (v - csum) + shi;      // keys in buckets strictly above my chunk
  for (int k = 15; k >= 0; --k) { run += hloc[k]; sufx[t * 16 + k] = run; }
  __syncthreads();
#pragma unroll
  for (int k = 0; k < 16; ++k) {
    int bb = t * 16 + k;
    unsigned s = sufx[bb];
    unsigned snxt = (bb + 1 < NB2) ? sufx[bb + 1] : 0u;
    if (s >= NPRE && snxt < NPRE) thrT = (unsigned)bb;   // unique
  }
  __syncthreads();
  unsigned T = thrT;

  // ---- P3: bucket-sorted compaction ----
  for (int k = 0; k < 16; ++k) {
    int base4 = k * 768 + 3 * t;
    float4 A = cb4[base4], Bq = cb4[base4 + 1], Cq = cb4[base4 + 2];
    float sc[4];
    sc[0] = fmaxf(A.x, fmaxf(A.y, A.z));
    sc[1] = fmaxf(A.w, fmaxf(Bq.x, Bq.y));
    sc[2] = fmaxf(Bq.z, fmaxf(Bq.w, Cq.x));
    sc[3] = fmaxf(Cq.y, fmaxf(Cq.z, Cq.w));
#pragma unroll
    for (int m = 0; m < 4; ++m) {
      int i = k * 1024 + 4 * t + m;
      unsigned u = mono_f32(sc[m]);
      unsigned bk = u >> 20;
      if (bk >= T) {
        unsigned lo = (bk + 1 < NB2) ? sufx[bk + 1] : 0u;
        unsigned pos = lo + atomicAdd(&tiec[bk], 1u);
        if (pos < SCAP) scand[pos] = (((ull)u) << 14) | (ull)(16383 - i);
      }
    }
  }
  __syncthreads();

  // ---- P4: exact rank via suffix base + same-bucket tiebreak ----
  unsigned C = sufx[T]; if (C > SCAP) C = SCAP;
  for (unsigned p = (unsigned)t; p < C; p += 256) {
    ull key = scand[p];
    unsigned bk = (unsigned)(key >> 34);
    unsigned lo = (bk + 1 < NB2) ? sufx[bk + 1] : 0u;
    unsigned hi = sufx[bk]; if (hi > SCAP) hi = SCAP;
    unsigned tie = 0;
    for (unsigned q = lo; q < hi; ++q) tie += (scand[q] > key) ? 1u : 0u;
    unsigned r = lo + tie;
    if (r < NPRE) rankIdx[r] = (unsigned)(16383u - (unsigned)(key & 0x3FFFULL));
  }
  __syncthreads();

  // ---- P5: geometry -> pinfoL/geomL (aliases tiec/scand), topi ----
  const float* boxb = box + (size_t)b * NBOX * 7;
  for (int r = t; r < NPRE; r += 256) {
    int idx = (int)rankIdx[r];
    topi[b * NPRE + r] = idx;            // redundant identical writes
    const float* bp = boxb + (size_t)idx * 7;
    float x = bp[0], y = bp[1], dx = bp[3], dy = bp[4], ry = bp[6];
    float c = cosf(ry), s = sinf(ry);
    float rad = 0.5f * sqrtf(dx * dx + dy * dy);
    float area = dx * dy;
    pinfoL[r] = make_float4(x, y, rad, area);
    geomL[r]  = make_float4(dx, dy, c, s);
  }
  __syncthreads();

  // ---- P6: cheap sweep over own rows (i == blk mod GPB) ----
  unsigned sbase = (unsigned)blockIdx.x * SEGCAP;
  for (int iter = 0; iter < 256; ++iter) {
    int task = iter * 4 + wv;            // 1024 wave-tasks: 64 rows x 16 words
    int q = task >> 4, w = task & 15;
    int i = q * GPB + blk;
    if (w * 64 + 63 <= i) continue;      // wave-uniform
    int j = w * 64 + lane;
    float4 pi = pinfoL[i];
    float4 pj = pinfoL[j];
    bool cnd = false;
    if (j > i) {
      float ddx = pi.x - pj.x, ddy = pi.y - pj.y;
      float rr = pi.z + pj.z + 1e-3f;
      if (ddx * ddx + ddy * ddy <= rr * rr) {            // not provably disjoint
        float mn = fminf(pi.w, pj.w), mx = fmaxf(pi.w, pj.w);
        if (mn > NMS_TH * mx) cnd = true;                // not provably iou<=0.8
      }
    }
    ull bal = __ballot(cnd);
    if (!bal) continue;
    unsigned base = 0;
    if (lane == 0) base = atomicAdd(&cntP, (unsigned)__popcll(bal));
    base = (unsigned)__shfl((int)base, 0, 64);
    if (cnd) {
      unsigned off = base + (unsigned)__popcll(bal & ((1ull << lane) - 1ull));
      unsigned pk = ((unsigned)i << 10) | (unsigned)j;
      if (off < CPAIR) candPk[off] = pk;
      else {                             // overflow: inline eval (rare-correct)
        if (iou_geom_gt(pi, geomL[i], pj, geomL[j])) {
          unsigned h = atomicAdd(&cntH, 1u);
          hitseg[sbase + h] = pk;
        }
      }
    }
  }
  __syncthreads();

  // ---- P7: dense exact IoU over compacted pairs ----
  unsigned P = cntP; if (P > CPAIR) P = CPAIR;
  for (unsigned e = (unsigned)t; e < P; e += 256) {
    unsigned pk = candPk[e];
    unsigned i = pk >> 10, j = pk & 1023u;
    if (iou_geom_gt(pinfoL[i], geomL[i], pinfoL[j], geomL[j])) {
      unsigned h = atomicAdd(&cntH, 1u);
      hitseg[sbase + h] = pk;            // h < SEGCAP by construction
    }
  }
  __syncthreads();
  if (t == 0) hitcnt[blockIdx.x] = (cntH < (unsigned)SEGCAP) ? cntH : (unsigned)SEGCAP;
}

__device__ __forceinline__ int popbelow(const unsigned* rowbm, int i) {
  int s = 0, w = i >> 5;
  for (int k = 0; k < w; ++k) s += __popc(rowbm[k]);
  s += __popc(rowbm[w] & ((1u << (i & 31)) - 1u));
  return s;
}

// =====================================================================
// K2: per-batch (512 thr): gather hits -> slot masks -> wave-0 greedy
//     walk -> compact + gather outputs.
// =====================================================================
__global__ __launch_bounds__(512) void k_fin(
    const float* __restrict__ box, const float* __restrict__ cls,
    const int* __restrict__ topi, const unsigned* __restrict__ hitseg,
    const unsigned* __restrict__ hitcnt, float* __restrict__ out, int B) {
  __shared__ unsigned maskL[128 * 32];   // 16 KB: 128 slots x 1024 bits
  __shared__ unsigned rlist[NPRE];       // 4 KB slot->row
  __shared__ unsigned segoff[GPB + 1];
  __shared__ unsigned rowbm[32];
  __shared__ ull remv_sh[16];
  __shared__ unsigned smallu[8];
  __shared__ unsigned rn_sh;

  const int b = blockIdx.x, t = threadIdx.x;
  const int lane = t & 63, wv = t >> 6;

  for (int k = t; k < 128 * 32; k += 512) maskL[k] = 0u;
  if (t < 32) rowbm[t] = 0u;
  if (t == 0) {
    unsigned o = 0;
    for (int s = 0; s < GPB; ++s) {
      segoff[s] = o;
      unsigned c = hitcnt[b * GPB + s];
      o += (c < (unsigned)SEGCAP) ? c : (unsigned)SEGCAP;
    }
    segoff[GPB] = o;
  }
  __syncthreads();
  unsigned H = segoff[GPB];

  // pass 1: row bitmap
  for (unsigned e = (unsigned)t; e < H; e += 512) {
    int lo = 0, hi = GPB - 1;
    while (lo < hi) { int mid = (lo + hi + 1) >> 1; if (segoff[mid] <= e) lo = mid; else hi = mid - 1; }
    unsigned pk = hitseg[((size_t)(b * GPB + lo)) * SEGCAP + (e - segoff[lo])];
    atomicOr(&rowbm[(pk >> 10) >> 5], 1u << ((pk >> 10) & 31));
  }
  __syncthreads();
  for (int row = t; row < NPRE; row += 512) {
    if ((rowbm[row >> 5] >> (row & 31)) & 1u)
      rlist[popbelow(rowbm, row)] = (unsigned)row;
  }
  if (t == 0) {
    unsigned s = 0;
    for (int w = 0; w < 32; ++w) s += (unsigned)__popc(rowbm[w]);
    rn_sh = s;
  }
  __syncthreads();
  // pass 2: slot masks
  for (unsigned e = (unsigned)t; e < H; e += 512) {
    int lo = 0, hi = GPB - 1;
    while (lo < hi) { int mid = (lo + hi + 1) >> 1; if (segoff[mid] <= e) lo = mid; else hi = mid - 1; }
    unsigned pk = hitseg[((size_t)(b * GPB + lo)) * SEGCAP + (e - segoff[lo])];
    unsigned i = pk >> 10, j = pk & 1023u;
    int slot = popbelow(rowbm, (int)i);
    if (slot < 128) atomicOr(&maskL[slot * 32 + (j >> 5)], 1u << (j & 31));
  }
  __syncthreads();

  // wave-0 greedy walk at LDS speed
  if (wv == 0) {
    ull remv = 0;                        // lane w<16 holds remv word w
    unsigned rn = rn_sh;
    for (unsigned s = 0; s < rn; ++s) {
      unsigned row = rlist[s];
      ull m = 0;
      if (s < 128) {
        if (lane < 16)
          m = (ull)maskL[s * 32 + lane * 2] | ((ull)maskL[s * 32 + lane * 2 + 1] << 32);
      } else {                           // slow-correct overflow: rescan hits
        for (unsigned e = 0; e < H; ++e) {
          int lo = 0, hi = GPB - 1;
          while (lo < hi) { int mid = (lo + hi + 1) >> 1; if (segoff[mid] <= e) lo = mid; else hi = mid - 1; }
          unsigned pk = hitseg[((size_t)(b * GPB + lo)) * SEGCAP + (e - segoff[lo])];
          if ((pk >> 10) == row) {
            unsigned j = pk & 1023u;
            if (lane == (int)(j >> 6)) m |= 1ull << (j & 63);
          }
        }
      }
      ull rw = __shfl(remv, (int)(row >> 6), 64);
      if (!((rw >> (row & 63)) & 1ULL)) remv |= m;
    }
    if (lane < 16) remv_sh[lane] = remv;
  }
  __syncthreads();

  // compact + gather (512 thr x 2 slots)
  int p0 = t * 2;
  ull rw = remv_sh[p0 >> 6];
  int a0 = ((rw >> (p0 & 63)) & 1ULL) ? 0 : 1;
  int a1 = ((rw >> ((p0 + 1) & 63)) & 1ULL) ? 0 : 1;
  int myc = a0 + a1;
  int v = myc;
#pragma unroll
  for (int off = 1; off < 64; off <<= 1) {
    int t2 = __shfl_up(v, off, 64);
    if (lane >= off) v += t2;
  }
  if (lane == 63) smallu[wv] = (unsigned)v;
  __syncthreads();
  int pre = 0;
  for (int w2 = 0; w2 < wv; ++w2) pre += (int)smallu[w2];
  int total = 0;
  for (int w2 = 0; w2 < 8; ++w2) total += (int)smallu[w2];
  int s = pre + v - myc;

  float* rois   = out;
  float* scores = out + (size_t)B * NPOST * 7;
  float* labels = scores + (size_t)B * NPOST;
  float* logits = labels + (size_t)B * NPOST;
  int aa[2] = {a0, a1};
#pragma unroll
  for (int k = 0; k < 2; ++k) {
    if (aa[k] && s < NPOST) {
      int orig = topi[b * NPRE + p0 + k];
      const float* bb = box + ((size_t)b * NBOX + orig) * 7;
      float* ro = rois + ((size_t)b * NPOST + s) * 7;
#pragma unroll
      for (int c2 = 0; c2 < 7; ++c2) ro[c2] = bb[c2];
      const float* cc = cls + ((size_t)b * NBOX + orig) * 3;
      float l0 = cc[0], l1 = cc[1], l2 = cc[2];
      float m = fmaxf(l0, fmaxf(l1, l2));
      int lab = (l0 == m) ? 0 : ((l1 == m) ? 1 : 2);   // argmax: first max
      scores[b * NPOST + s] = m;
      labels[b * NPOST + s] = (float)(lab + 1);
      float* lg = logits + ((size_t)b * NPOST + s) * 3;
      lg[0] = l0; lg[1] = l1; lg[2] = l2;
    }
    s += aa[k];
  }
  if (t < NPOST && t >= total) {         // invalid slots: zeros, label 1
    float* ro = rois + ((size_t)b * NPOST + t) * 7;
#pragma unroll
    for (int c2 = 0; c2 < 7; ++c2) ro[c2] = 0.f;
    scores[b * NPOST + t] = 0.f;
    labels[b * NPOST + t] = 1.f;
    float* lg = logits + ((size_t)b * NPOST + t) * 3;
    lg[0] = 0.f; lg[1] = 0.f; lg[2] = 0.f;
  }
}

extern "C" void kernel_launch(void* const* d_in, const int* in_sizes, int n_in,
                              void* d_out, int out_size, void* d_ws, size_t ws_size,
                              hipStream_t stream) {
  const float* box = (const float*)d_in[0];
  const float* cls = (const float*)d_in[1];
  float* out = (float*)d_out;
  int B = in_sizes[0] / (NBOX * 7);    // == 2

  char* w = (char*)d_ws;
  size_t off = 0;
  int* topi        = (int*)(w + off);      off += (size_t)B * NPRE * sizeof(int);
  unsigned* hitcnt = (unsigned*)(w + off); off += (size_t)B * GPB * sizeof(unsigned);
  off = (off + 63) & ~(size_t)63;
  unsigned* hitseg = (unsigned*)(w + off); off += (size_t)B * GPB * SEGCAP * sizeof(unsigned);
  (void)off; (void)ws_size; (void)out_size; (void)n_in;

  hipLaunchKernelGGL(k_mega, dim3(B * GPB), dim3(256), 0, stream, box, cls, topi, hitseg, hitcnt);
  hipLaunchKernelGGL(k_fin,  dim3(B),       dim3(512), 0, stream, box, cls, topi, hitseg, hitcnt, out, B);
}

// Round 12
// 133.511 us; speedup vs baseline: 1.4292x; 1.4292x over previous
//
#include <hip/hip_runtime.h>
#include <hip/hip_bf16.h>
#include <math.h>

#define NBOX   16384
#define NPRE   1024
#define NPOST  512
#define NMS_TH 0.8f
#define DEN_EPS 1e-8f
#define NCAND  2048            // candidate LDS buffer (threshold-bucket slack)
#define NBUCK  8192            // 13-bit histogram buckets
#define SEGCAP 16384           // per-block hit segment (worst case 16368)
#define CANDL  2048            // per-block LDS candidate cap

typedef unsigned long long ull;

__device__ __forceinline__ unsigned mono_f32(float a) {
  unsigned u = __float_as_uint(a);
  return (u & 0x80000000u) ? ~u : (u | 0x80000000u);
}

// =====================================================================
// K1: per-slice top-k select. grid = B*8, 256 thr. (R10-proven)
// Redundant full LDS histogram -> identical threshold T -> ballot-compact
// own 2048-key slice into private segment + count. Also zeroes ticket.
// key = (mono(score) << 14) | (16383 - i): u64 '>' == top_k order.
// =====================================================================
__global__ __launch_bounds__(256) void k_sel(
    const float* __restrict__ cls, ull* __restrict__ cand,
    unsigned* __restrict__ candCnt, unsigned* __restrict__ done) {
  __shared__ unsigned hist[NBUCK];     // 32 KB
  __shared__ unsigned smallu[8];
  __shared__ unsigned thrT, cntL;
  const int b = blockIdx.x >> 3, s = blockIdx.x & 7;
  const int t = threadIdx.x;
  const int lane = t & 63, wv = t >> 6;
  const float* cb = cls + (size_t)b * NBOX * 3;

  if (blockIdx.x == 0 && t < 64) done[t] = 0u;   // zero ticket counters
#pragma unroll
  for (int k = 0; k < NBUCK / 256; ++k) hist[t + k * 256] = 0u;
  if (t == 0) cntL = 0u;
  __syncthreads();

  for (int k = 0; k < 64; ++k) {       // full histogram (deterministic)
    int i = k * 256 + t;
    float sc = fmaxf(cb[i * 3], fmaxf(cb[i * 3 + 1], cb[i * 3 + 2]));
    atomicAdd(&hist[mono_f32(sc) >> 19], 1u);
  }
  __syncthreads();

  unsigned csum = 0;                   // threshold: suffix scan, 32 bkt/thr
#pragma unroll 8
  for (int k = 0; k < 32; ++k) csum += hist[t * 32 + k];
  unsigned v = csum;
#pragma unroll
  for (int off = 1; off < 64; off <<= 1) {
    unsigned o = __shfl_down((int)v, off, 64);
    if (lane + off < 64) v += o;
  }
  if (lane == 0) smallu[wv] = v;
  __syncthreads();
  unsigned shi = 0;
  for (int w2 = wv + 1; w2 < 4; ++w2) shi += smallu[w2];
  unsigned incl = v + shi;
  unsigned safter = incl - csum;
  if (safter < NPRE && incl >= NPRE) { // unique crossing chunk
    unsigned c = safter;
    for (int k = 31; k >= 0; --k) {
      c += hist[t * 32 + k];
      if (c >= NPRE) { thrT = (unsigned)(t * 32 + k); break; }
    }
  }
  __syncthreads();
  unsigned T = thrT;

  ull* seg = cand + ((size_t)b * 8 + s) * 2048;
  for (int k = s * 8; k < s * 8 + 8; ++k) {
    int i = k * 256 + t;
    float sc = fmaxf(cb[i * 3], fmaxf(cb[i * 3 + 1], cb[i * 3 + 2]));
    unsigned u = mono_f32(sc);
    bool cnd = (u >> 19) >= T;
    ull bal = __ballot(cnd);
    if (bal) {
      unsigned base = 0;
      if (lane == 0) base = atomicAdd(&cntL, (unsigned)__popcll(bal));
      base = (unsigned)__shfl((int)base, 0, 64);
      if (cnd) {
        unsigned pos = base + (unsigned)__popcll(bal & ((1ull << lane) - 1ull));
        seg[pos] = (((ull)u) << 14) | (ull)(16383 - i);
      }
    }
  }
  __syncthreads();
  if (t == 0) candCnt[b * 8 + s] = cntL;
}

// =====================================================================
// K2: rank candidates -> topi, binfo, pinfo. grid = B*8, 256 thr. (R10)
// binfo row (16 f): x,y,dx,dy,cos,sin,cx[4],cy[4],circumrad,area
// =====================================================================
__global__ __launch_bounds__(256) void k_rank(
    const float* __restrict__ box, const ull* __restrict__ cand,
    const unsigned* __restrict__ candCnt,
    int* __restrict__ topi, float* __restrict__ binfo, float4* __restrict__ pinfoG) {
  __shared__ ull candL[NCAND];         // 16 KB
  __shared__ unsigned offs[9];
  const int b = blockIdx.x >> 3, g = blockIdx.x & 7;
  const int t = threadIdx.x;

  if (t == 0) {
    unsigned o = 0;
    for (int s = 0; s < 8; ++s) {
      offs[s] = o;
      unsigned c = candCnt[b * 8 + s];
      o += (c < 2048u) ? c : 2048u;
    }
    offs[8] = o;
  }
  __syncthreads();
  unsigned C = offs[8]; if (C > NCAND) C = NCAND;
  for (int s = 0; s < 8; ++s) {
    unsigned base = offs[s], cnt = offs[s + 1] - offs[s];
    const ull* seg = cand + ((size_t)b * 8 + s) * 2048;
    for (unsigned e = (unsigned)t; e < cnt; e += 256) {
      unsigned dst = base + e;
      if (dst < NCAND) candL[dst] = seg[e];
    }
  }
  if (t < 2 && C + t < NCAND) candL[C + t] = 0ull;   // zero read-pad
  __syncthreads();

  int j = g * 256 + t;
  ull my = ((unsigned)j < C) ? candL[j] : 0ull;
  int r = 0;
  int kmax = (int)((C + 1) >> 1);
  const ulonglong2* p2 = (const ulonglong2*)candL;
  for (int k = 0; k < kmax; ++k) {
    ulonglong2 kk = p2[k];
    r += (kk.x > my) ? 1 : 0;
    r += (kk.y > my) ? 1 : 0;
  }
  if ((unsigned)j >= C || r >= NPRE) return;
  int i = 16383 - (int)(my & 0x3FFFULL);
  topi[b * NPRE + r] = i;
  const float* bp = box + ((size_t)b * NBOX + i) * 7;
  float x = bp[0], y = bp[1], dx = bp[3], dy = bp[4], ry = bp[6];
  float c = cosf(ry), s = sinf(ry);
  float* o = binfo + ((size_t)b * NPRE + r) * 16;
  o[0] = x; o[1] = y; o[2] = dx; o[3] = dy; o[4] = c; o[5] = s;
  const float offx[4] = {0.5f, -0.5f, -0.5f, 0.5f};
  const float offy[4] = {0.5f, 0.5f, -0.5f, -0.5f};
#pragma unroll
  for (int k = 0; k < 4; ++k) {
    float lx = dx * offx[k], ly = dy * offy[k];
    o[6 + k]  = x + lx * c - ly * s;
    o[10 + k] = y + lx * s + ly * c;
  }
  float rad = 0.5f * sqrtf(dx * dx + dy * dy);
  float area = dx * dy;
  o[14] = rad; o[15] = area;
  pinfoG[(size_t)b * NPRE + r] = make_float4(x, y, rad, area);
}

// =====================================================================
// exact rotated IoU > thresh, register-only (reference-exact semantics)
// Stable argsort by (angle,idx) == successor chain on key=(mono(ang)<<5)|idx;
// polygon area = sum of cross(p, succ(p)), wrap to global min key.
// =====================================================================
__device__ bool iou_exact_gt(const float* __restrict__ Ab, const float* __restrict__ Bb) {
  float ax = Ab[0], ay = Ab[1], bx = Bb[0], by = Bb[1];
  float aA = Ab[15], aB = Bb[15];
  float acx[4], acy[4], bcx[4], bcy[4];
#pragma unroll
  for (int k = 0; k < 4; ++k) {
    acx[k] = Ab[6 + k]; acy[k] = Ab[10 + k];
    bcx[k] = Bb[6 + k]; bcy[k] = Bb[10 + k];
  }
  float px[24], py[24];
  bool act[24];
#pragma unroll
  for (int p = 0; p < 4; ++p) {
    float A0x = acx[p], A0y = acy[p];
    float DAx = acx[(p + 1) & 3] - A0x, DAy = acy[(p + 1) & 3] - A0y;
#pragma unroll
    for (int q = 0; q < 4; ++q) {
      float B0x = bcx[q], B0y = bcy[q];
      float DBx = bcx[(q + 1) & 3] - B0x, DBy = bcy[(q + 1) & 3] - B0y;
      float den = DAx * DBy - DAy * DBx;
      float dxx = B0x - A0x, dyy = B0y - A0y;
      bool dok = fabsf(den) > DEN_EPS;
      float dens = dok ? den : 1.0f;
      float t = (dxx * DBy - dyy * DBx) / dens;
      float u = (dxx * DAy - dyy * DAx) / dens;
      int k = p * 4 + q;
      px[k] = A0x + t * DAx;
      py[k] = A0y + t * DAy;
      act[k] = dok && t >= 0.f && t <= 1.f && u >= 0.f && u <= 1.f;
    }
  }
  float cA = Ab[4], sA = Ab[5], cB = Bb[4], sB = Bb[5];
#pragma unroll
  for (int k = 0; k < 4; ++k) {
    float rx = acx[k] - bx, ry = acy[k] - by;
    float qx =  rx * cB + ry * sB, qy = -rx * sB + ry * cB;
    px[16 + k] = acx[k]; py[16 + k] = acy[k];
    act[16 + k] = (fabsf(qx) <= Bb[2] * 0.5f + 1e-5f) && (fabsf(qy) <= Bb[3] * 0.5f + 1e-5f);
  }
#pragma unroll
  for (int k = 0; k < 4; ++k) {
    float rx = bcx[k] - ax, ry = bcy[k] - ay;
    float qx =  rx * cA + ry * sA, qy = -rx * sA + ry * cA;
    px[20 + k] = bcx[k]; py[20 + k] = bcy[k];
    act[20 + k] = (fabsf(qx) <= Ab[2] * 0.5f + 1e-5f) && (fabsf(qy) <= Ab[3] * 0.5f + 1e-5f);
  }
  int cnt = 0; float sx = 0.f, sy = 0.f;
#pragma unroll
  for (int k = 0; k < 24; ++k)
    if (act[k]) { cnt++; sx += px[k]; sy += py[k]; }
  float fc = (float)(cnt > 1 ? cnt : 1);
  float cx0 = sx / fc, cy0 = sy / fc;
  ull key[24];
#pragma unroll
  for (int k = 0; k < 24; ++k) {
    float ang = atan2f(py[k] - cy0, px[k] - cx0);
    key[k] = act[k] ? ((((ull)mono_f32(ang)) << 5) | (ull)k) : ~0ull;
  }
  ull kmin = ~0ull; float fx = 0.f, fy = 0.f;
#pragma unroll
  for (int k = 0; k < 24; ++k) {
    bool lt = key[k] < kmin;
    kmin = lt ? key[k] : kmin;
    fx = lt ? px[k] : fx;
    fy = lt ? py[k] : fy;
  }
  float ssum = 0.f;
#pragma unroll
  for (int k = 0; k < 24; ++k) {
    ull myk = key[k];
    ull best = ~0ull; float nx = fx, ny = fy;   // default: wrap to first
#pragma unroll
    for (int j = 0; j < 24; ++j) {
      bool c = (key[j] > myk) && (key[j] < best);
      best = c ? key[j] : best;
      nx = c ? px[j] : nx;
      ny = c ? py[j] : ny;
    }
    float contrib = px[k] * ny - py[k] * nx;
    ssum += (myk != ~0ull) ? contrib : 0.f;
  }
  float inter = 0.5f * fabsf(ssum);
  float uni = aA + aB - inter;
  return inter / fmaxf(uni, 1e-6f) > NMS_TH;
}

__device__ __forceinline__ int popbelow(const unsigned* rowbm, int i) {
  int s = 0, w = i >> 5;
  for (int k = 0; k < w; ++k) s += __popc(rowbm[k]);
  s += __popc(rowbm[w] & ((1u << (i & 31)) - 1u));
  return s;
}

// =====================================================================
// K3: cheap sweep -> dense exact IoU -> hit segment; LAST block per batch
//     runs the NMS + compact + gather epilogue (ticket pattern).
// grid = B*64, 256 thr. Block handles rows i == blk (mod 64).
// =====================================================================
__global__ __launch_bounds__(256) void k_pairsfin(
    const float4* __restrict__ pinfoG, const float* __restrict__ binfo,
    const float* __restrict__ box, const float* __restrict__ cls,
    const int* __restrict__ topi,
    unsigned* __restrict__ hitseg, unsigned* __restrict__ hitcnt,
    unsigned* __restrict__ done, float* __restrict__ out, int B) {
  __shared__ float4 pin[NPRE];         // 16 KB; epilogue aliases -> maskL
  __shared__ unsigned candL[CANDL];    // 8 KB;  epilogue aliases -> rlist+
  __shared__ unsigned cntC, cntH;
  __shared__ int amLast;
  const int b = blockIdx.x >> 6, blk = blockIdx.x & 63;
  const int t = threadIdx.x;
  const int lane = t & 63, wv = t >> 6;
#pragma unroll
  for (int k = 0; k < 4; ++k) pin[k * 256 + t] = pinfoG[(size_t)b * NPRE + k * 256 + t];
  if (t == 0) { cntC = 0u; cntH = 0u; }
  __syncthreads();

  const float* bi = binfo + (size_t)b * NPRE * 16;
  unsigned sbase = ((unsigned)b * 64 + (unsigned)blk) * SEGCAP;
  for (int iter = 0; iter < 64; ++iter) {
    int task = iter * 4 + wv;          // 256 wave-tasks: 16 rows x 16 words
    int q = task >> 4, w = task & 15;
    int i = q * 64 + blk;
    if (w * 64 + 63 <= i) continue;    // wave-uniform
    int j = w * 64 + lane;
    float4 pi = pin[i];
    float4 pj = pin[j];
    bool cnd = false;
    if (j > i) {
      float ddx = pi.x - pj.x, ddy = pi.y - pj.y;
      float rr = pi.z + pj.z + 1e-3f;
      if (ddx * ddx + ddy * ddy <= rr * rr) {            // not provably disjoint
        float mn = fminf(pi.w, pj.w), mx = fmaxf(pi.w, pj.w);
        if (mn > NMS_TH * mx) cnd = true;                // not provably iou<=0.8
      }
    }
    ull bal = __ballot(cnd);
    if (!bal) continue;
    unsigned base = 0;
    if (lane == 0) base = atomicAdd(&cntC, (unsigned)__popcll(bal));
    base = (unsigned)__shfl((int)base, 0, 64);
    if (cnd) {
      unsigned off = base + (unsigned)__popcll(bal & ((1ull << lane) - 1ull));
      unsigned pk = ((unsigned)i << 10) | (unsigned)j;
      if (off < CANDL) candL[off] = pk;
      else {                           // LDS overflow: inline eval (rare-correct)
        if (iou_exact_gt(bi + (size_t)i * 16, bi + (size_t)j * 16)) {
          unsigned h = atomicAdd(&cntH, 1u);
          hitseg[sbase + h] = pk;      // h < SEGCAP by construction (<=16368)
        }
      }
    }
  }
  __syncthreads();

  // dense exact IoU over this block's compacted candidates
  unsigned C = cntC; if (C > CANDL) C = CANDL;
  for (unsigned e = (unsigned)t; e < C; e += 256) {
    unsigned pk = candL[e];
    unsigned i = pk >> 10, j = pk & 1023u;
    if (iou_exact_gt(bi + (size_t)i * 16, bi + (size_t)j * 16)) {
      unsigned h = atomicAdd(&cntH, 1u);
      hitseg[sbase + h] = pk;
    }
  }
  __syncthreads();
  if (t == 0) {
    hitcnt[b * 64 + blk] = (cntH < (unsigned)SEGCAP) ? cntH : (unsigned)SEGCAP;
    __threadfence();                   // release: hitseg/hitcnt device-visible
    unsigned old = atomicAdd(&done[b], 1u);
    amLast = (old == 63u) ? 1 : 0;
  }
  __syncthreads();
  if (!amLast) return;
  __threadfence();                     // acquire on the last block

  // ================= epilogue: NMS walk + compact + gather =================
  unsigned* maskL = (unsigned*)pin;    // 16 KB: 128 slots x 1024 bits
  unsigned* rlist = candL;             // 4 KB of candL: slot -> row
  __shared__ unsigned segoff[65];
  __shared__ unsigned rowbm[32];
  __shared__ ull remv_sh[16];
  __shared__ unsigned smallu[4];
  __shared__ unsigned rn_sh;

  for (int k = t; k < 128 * 32; k += 256) maskL[k] = 0u;
  if (t < 32) rowbm[t] = 0u;
  if (t == 0) {
    unsigned o = 0;
    for (int s = 0; s < 64; ++s) {
      segoff[s] = o;
      unsigned c = hitcnt[b * 64 + s];
      o += (c < (unsigned)SEGCAP) ? c : (unsigned)SEGCAP;
    }
    segoff[64] = o;
  }
  __syncthreads();
  unsigned H = segoff[64];

  // pass 1: row bitmap
  for (unsigned e = (unsigned)t; e < H; e += 256) {
    int lo = 0, hi = 63;
    while (lo < hi) { int mid = (lo + hi + 1) >> 1; if (segoff[mid] <= e) lo = mid; else hi = mid - 1; }
    unsigned pk = hitseg[((size_t)(b * 64 + lo)) * SEGCAP + (e - segoff[lo])];
    atomicOr(&rowbm[(pk >> 10) >> 5], 1u << ((pk >> 10) & 31));
  }
  __syncthreads();
  for (int row = t; row < NPRE; row += 256) {
    if ((rowbm[row >> 5] >> (row & 31)) & 1u)
      rlist[popbelow(rowbm, row)] = (unsigned)row;
  }
  if (t == 0) {
    unsigned s = 0;
    for (int w = 0; w < 32; ++w) s += (unsigned)__popc(rowbm[w]);
    rn_sh = s;
  }
  __syncthreads();
  // pass 2: slot masks
  for (unsigned e = (unsigned)t; e < H; e += 256) {
    int lo = 0, hi = 63;
    while (lo < hi) { int mid = (lo + hi + 1) >> 1; if (segoff[mid] <= e) lo = mid; else hi = mid - 1; }
    unsigned pk = hitseg[((size_t)(b * 64 + lo)) * SEGCAP + (e - segoff[lo])];
    unsigned i = pk >> 10, j = pk & 1023u;
    int slot = popbelow(rowbm, (int)i);
    if (slot < 128) atomicOr(&maskL[slot * 32 + (j >> 5)], 1u << (j & 31));
  }
  __syncthreads();

  // wave-0 greedy walk at LDS speed
  if (wv == 0) {
    ull remv = 0;                        // lane w<16 holds remv word w
    unsigned rn = rn_sh;
    for (unsigned s = 0; s < rn; ++s) {
      unsigned row = rlist[s];
      ull m = 0;
      if (s < 128) {
        if (lane < 16)
          m = (ull)maskL[s * 32 + lane * 2] | ((ull)maskL[s * 32 + lane * 2 + 1] << 32);
      } else {                           // slow-correct overflow: rescan hits
        for (unsigned e = 0; e < H; ++e) {
          int lo = 0, hi = 63;
          while (lo < hi) { int mid = (lo + hi + 1) >> 1; if (segoff[mid] <= e) lo = mid; else hi = mid - 1; }
          unsigned pk = hitseg[((size_t)(b * 64 + lo)) * SEGCAP + (e - segoff[lo])];
          if ((pk >> 10) == row) {
            unsigned j = pk & 1023u;
            if (lane == (int)(j >> 6)) m |= 1ull << (j & 63);
          }
        }
      }
      ull rw = __shfl(remv, (int)(row >> 6), 64);
      if (!((rw >> (row & 63)) & 1ULL)) remv |= m;
    }
    if (lane < 16) remv_sh[lane] = remv;
  }
  __syncthreads();

  // compact + gather (256 thr x 4 slots; R7-verified shape)
  int p0 = t * 4;
  ull rw = remv_sh[p0 >> 6];
  int a0 = ((rw >> ((p0 + 0) & 63)) & 1ULL) ? 0 : 1;
  int a1 = ((rw >> ((p0 + 1) & 63)) & 1ULL) ? 0 : 1;
  int a2 = ((rw >> ((p0 + 2) & 63)) & 1ULL) ? 0 : 1;
  int a3 = ((rw >> ((p0 + 3) & 63)) & 1ULL) ? 0 : 1;
  int myc = a0 + a1 + a2 + a3;
  int v = myc;
#pragma unroll
  for (int off = 1; off < 64; off <<= 1) {
    int t2 = __shfl_up(v, off, 64);
    if (lane >= off) v += t2;
  }
  if (lane == 63) smallu[wv] = (unsigned)v;
  __syncthreads();
  int pre = 0;
  for (int w2 = 0; w2 < wv; ++w2) pre += (int)smallu[w2];
  int total = (int)(smallu[0] + smallu[1] + smallu[2] + smallu[3]);
  int s = pre + v - myc;

  float* rois   = out;
  float* scores = out + (size_t)B * NPOST * 7;
  float* labels = scores + (size_t)B * NPOST;
  float* logits = labels + (size_t)B * NPOST;
  int aa[4] = {a0, a1, a2, a3};
#pragma unroll
  for (int k = 0; k < 4; ++k) {
    if (aa[k] && s < NPOST) {
      int orig = topi[b * NPRE + p0 + k];
      const float* bb = box + ((size_t)b * NBOX + orig) * 7;
      float* ro = rois + ((size_t)b * NPOST + s) * 7;
#pragma unroll
      for (int c2 = 0; c2 < 7; ++c2) ro[c2] = bb[c2];
      const float* cc = cls + ((size_t)b * NBOX + orig) * 3;
      float l0 = cc[0], l1 = cc[1], l2 = cc[2];
      float m = fmaxf(l0, fmaxf(l1, l2));
      int lab = (l0 == m) ? 0 : ((l1 == m) ? 1 : 2);   // argmax: first max
      scores[b * NPOST + s] = m;
      labels[b * NPOST + s] = (float)(lab + 1);
      float* lg = logits + ((size_t)b * NPOST + s) * 3;
      lg[0] = l0; lg[1] = l1; lg[2] = l2;
    }
    s += aa[k];
  }
  for (int p2 = t; p2 < NPOST; p2 += 256) {
    if (p2 >= total) {                   // invalid slots: zeros, label 1
      float* ro = rois + ((size_t)b * NPOST + p2) * 7;
#pragma unroll
      for (int c2 = 0; c2 < 7; ++c2) ro[c2] = 0.f;
      scores[b * NPOST + p2] = 0.f;
      labels[b * NPOST + p2] = 1.f;
      float* lg = logits + ((size_t)b * NPOST + p2) * 3;
      lg[0] = 0.f; lg[1] = 0.f; lg[2] = 0.f;
    }
  }
}

extern "C" void kernel_launch(void* const* d_in, const int* in_sizes, int n_in,
                              void* d_out, int out_size, void* d_ws, size_t ws_size,
                              hipStream_t stream) {
  const float* box = (const float*)d_in[0];
  const float* cls = (const float*)d_in[1];
  float* out = (float*)d_out;
  int B = in_sizes[0] / (NBOX * 7);    // == 2

  char* w = (char*)d_ws;
  size_t off = 0;
  ull* cand        = (ull*)(w + off);      off += (size_t)B * 8 * 2048 * sizeof(ull);
  unsigned* candCt = (unsigned*)(w + off); off += (size_t)B * 8 * sizeof(unsigned);
  int* topi        = (int*)(w + off);      off += (size_t)B * NPRE * sizeof(int);
  unsigned* hitcnt = (unsigned*)(w + off); off += (size_t)B * 64 * sizeof(unsigned);
  unsigned* done   = (unsigned*)(w + off); off += 64 * sizeof(unsigned);
  off = (off + 63) & ~(size_t)63;
  float* binfo     = (float*)(w + off);    off += (size_t)B * NPRE * 16 * sizeof(float);
  float4* pinfoG   = (float4*)(w + off);   off += (size_t)B * NPRE * sizeof(float4);
  unsigned* hitseg = (unsigned*)(w + off); off += (size_t)B * 64 * SEGCAP * sizeof(unsigned);
  (void)off; (void)ws_size; (void)out_size; (void)n_in;

  hipLaunchKernelGGL(k_sel,      dim3(B * 8),  dim3(256), 0, stream, cls, cand, candCt, done);
  hipLaunchKernelGGL(k_rank,     dim3(B * 8),  dim3(256), 0, stream, box, cand, candCt, topi, binfo, pinfoG);
  hipLaunchKernelGGL(k_pairsfin, dim3(B * 64), dim3(256), 0, stream, pinfoG, binfo, box, cls, topi,
                     hitseg, hitcnt, done, out, B);
}

// Round 13
// 127.603 us; speedup vs baseline: 1.4954x; 1.0463x over previous
//
#include <hip/hip_runtime.h>
#include <hip/hip_bf16.h>
#include <math.h>

#define NBOX   16384
#define NPRE   1024
#define NPOST  512
#define NMS_TH 0.8f
#define DEN_EPS 1e-8f
#define NCAND  2048            // candidate LDS buffer (threshold-bucket slack)
#define NBUCK  8192            // 13-bit histogram buckets
#define SEGCAP 16384           // per-block hit segment (worst case 16368)
#define CANDL  2048            // per-block LDS candidate cap

typedef unsigned long long ull;

__device__ __forceinline__ unsigned mono_f32(float a) {
  unsigned u = __float_as_uint(a);
  return (u & 0x80000000u) ? ~u : (u | 0x80000000u);
}

// =====================================================================
// K1: per-slice top-k select. grid = B*8, 256 thr. (R10-proven)
// =====================================================================
__global__ __launch_bounds__(256) void k_sel(
    const float* __restrict__ cls, ull* __restrict__ cand,
    unsigned* __restrict__ candCnt, unsigned* __restrict__ done) {
  __shared__ unsigned hist[NBUCK];     // 32 KB
  __shared__ unsigned smallu[8];
  __shared__ unsigned thrT, cntL;
  const int b = blockIdx.x >> 3, s = blockIdx.x & 7;
  const int t = threadIdx.x;
  const int lane = t & 63, wv = t >> 6;
  const float* cb = cls + (size_t)b * NBOX * 3;

  if (blockIdx.x == 0 && t < 64) done[t] = 0u;   // zero ticket counters
#pragma unroll
  for (int k = 0; k < NBUCK / 256; ++k) hist[t + k * 256] = 0u;
  if (t == 0) cntL = 0u;
  __syncthreads();

  for (int k = 0; k < 64; ++k) {       // full histogram (deterministic)
    int i = k * 256 + t;
    float sc = fmaxf(cb[i * 3], fmaxf(cb[i * 3 + 1], cb[i * 3 + 2]));
    atomicAdd(&hist[mono_f32(sc) >> 19], 1u);
  }
  __syncthreads();

  unsigned csum = 0;                   // threshold: suffix scan, 32 bkt/thr
#pragma unroll 8
  for (int k = 0; k < 32; ++k) csum += hist[t * 32 + k];
  unsigned v = csum;
#pragma unroll
  for (int off = 1; off < 64; off <<= 1) {
    unsigned o = __shfl_down((int)v, off, 64);
    if (lane + off < 64) v += o;
  }
  if (lane == 0) smallu[wv] = v;
  __syncthreads();
  unsigned shi = 0;
  for (int w2 = wv + 1; w2 < 4; ++w2) shi += smallu[w2];
  unsigned incl = v + shi;
  unsigned safter = incl - csum;
  if (safter < NPRE && incl >= NPRE) { // unique crossing chunk
    unsigned c = safter;
    for (int k = 31; k >= 0; --k) {
      c += hist[t * 32 + k];
      if (c >= NPRE) { thrT = (unsigned)(t * 32 + k); break; }
    }
  }
  __syncthreads();
  unsigned T = thrT;

  ull* seg = cand + ((size_t)b * 8 + s) * 2048;
  for (int k = s * 8; k < s * 8 + 8; ++k) {
    int i = k * 256 + t;
    float sc = fmaxf(cb[i * 3], fmaxf(cb[i * 3 + 1], cb[i * 3 + 2]));
    unsigned u = mono_f32(sc);
    bool cnd = (u >> 19) >= T;
    ull bal = __ballot(cnd);
    if (bal) {
      unsigned base = 0;
      if (lane == 0) base = atomicAdd(&cntL, (unsigned)__popcll(bal));
      base = (unsigned)__shfl((int)base, 0, 64);
      if (cnd) {
        unsigned pos = base + (unsigned)__popcll(bal & ((1ull << lane) - 1ull));
        seg[pos] = (((ull)u) << 14) | (ull)(16383 - i);
      }
    }
  }
  __syncthreads();
  if (t == 0) candCnt[b * 8 + s] = cntL;
}

// =====================================================================
// K2: rank candidates -> topi, binfo, pinfo. grid = B*8, 256 thr. (R10)
// binfo row (16 f): x,y,dx,dy,cos,sin,cx[4],cy[4],circumrad,area
// =====================================================================
__global__ __launch_bounds__(256) void k_rank(
    const float* __restrict__ box, const ull* __restrict__ cand,
    const unsigned* __restrict__ candCnt,
    int* __restrict__ topi, float* __restrict__ binfo, float4* __restrict__ pinfoG) {
  __shared__ ull candL[NCAND];         // 16 KB
  __shared__ unsigned offs[9];
  const int b = blockIdx.x >> 3, g = blockIdx.x & 7;
  const int t = threadIdx.x;

  if (t == 0) {
    unsigned o = 0;
    for (int s = 0; s < 8; ++s) {
      offs[s] = o;
      unsigned c = candCnt[b * 8 + s];
      o += (c < 2048u) ? c : 2048u;
    }
    offs[8] = o;
  }
  __syncthreads();
  unsigned C = offs[8]; if (C > NCAND) C = NCAND;
  for (int s = 0; s < 8; ++s) {
    unsigned base = offs[s], cnt = offs[s + 1] - offs[s];
    const ull* seg = cand + ((size_t)b * 8 + s) * 2048;
    for (unsigned e = (unsigned)t; e < cnt; e += 256) {
      unsigned dst = base + e;
      if (dst < NCAND) candL[dst] = seg[e];
    }
  }
  if (t < 2 && C + t < NCAND) candL[C + t] = 0ull;   // zero read-pad
  __syncthreads();

  int j = g * 256 + t;
  ull my = ((unsigned)j < C) ? candL[j] : 0ull;
  int r = 0;
  int kmax = (int)((C + 1) >> 1);
  const ulonglong2* p2 = (const ulonglong2*)candL;
  for (int k = 0; k < kmax; ++k) {
    ulonglong2 kk = p2[k];
    r += (kk.x > my) ? 1 : 0;
    r += (kk.y > my) ? 1 : 0;
  }
  if ((unsigned)j >= C || r >= NPRE) return;
  int i = 16383 - (int)(my & 0x3FFFULL);
  topi[b * NPRE + r] = i;
  const float* bp = box + ((size_t)b * NBOX + i) * 7;
  float x = bp[0], y = bp[1], dx = bp[3], dy = bp[4], ry = bp[6];
  float c = cosf(ry), s = sinf(ry);
  float* o = binfo + ((size_t)b * NPRE + r) * 16;
  o[0] = x; o[1] = y; o[2] = dx; o[3] = dy; o[4] = c; o[5] = s;
  const float offx[4] = {0.5f, -0.5f, -0.5f, 0.5f};
  const float offy[4] = {0.5f, 0.5f, -0.5f, -0.5f};
#pragma unroll
  for (int k = 0; k < 4; ++k) {
    float lx = dx * offx[k], ly = dy * offy[k];
    o[6 + k]  = x + lx * c - ly * s;
    o[10 + k] = y + lx * s + ly * c;
  }
  float rad = 0.5f * sqrtf(dx * dx + dy * dy);
  float area = dx * dy;
  o[14] = rad; o[15] = area;
  pinfoG[(size_t)b * NPRE + r] = make_float4(x, y, rad, area);
}

// =====================================================================
// exact rotated IoU > thresh, register-only (reference-exact semantics)
// =====================================================================
__device__ bool iou_exact_gt(const float* __restrict__ Ab, const float* __restrict__ Bb) {
  float ax = Ab[0], ay = Ab[1], bx = Bb[0], by = Bb[1];
  float aA = Ab[15], aB = Bb[15];
  float acx[4], acy[4], bcx[4], bcy[4];
#pragma unroll
  for (int k = 0; k < 4; ++k) {
    acx[k] = Ab[6 + k]; acy[k] = Ab[10 + k];
    bcx[k] = Bb[6 + k]; bcy[k] = Bb[10 + k];
  }
  float px[24], py[24];
  bool act[24];
#pragma unroll
  for (int p = 0; p < 4; ++p) {
    float A0x = acx[p], A0y = acy[p];
    float DAx = acx[(p + 1) & 3] - A0x, DAy = acy[(p + 1) & 3] - A0y;
#pragma unroll
    for (int q = 0; q < 4; ++q) {
      float B0x = bcx[q], B0y = bcy[q];
      float DBx = bcx[(q + 1) & 3] - B0x, DBy = bcy[(q + 1) & 3] - B0y;
      float den = DAx * DBy - DAy * DBx;
      float dxx = B0x - A0x, dyy = B0y - A0y;
      bool dok = fabsf(den) > DEN_EPS;
      float dens = dok ? den : 1.0f;
      float t = (dxx * DBy - dyy * DBx) / dens;
      float u = (dxx * DAy - dyy * DAx) / dens;
      int k = p * 4 + q;
      px[k] = A0x + t * DAx;
      py[k] = A0y + t * DAy;
      act[k] = dok && t >= 0.f && t <= 1.f && u >= 0.f && u <= 1.f;
    }
  }
  float cA = Ab[4], sA = Ab[5], cB = Bb[4], sB = Bb[5];
#pragma unroll
  for (int k = 0; k < 4; ++k) {
    float rx = acx[k] - bx, ry = acy[k] - by;
    float qx =  rx * cB + ry * sB, qy = -rx * sB + ry * cB;
    px[16 + k] = acx[k]; py[16 + k] = acy[k];
    act[16 + k] = (fabsf(qx) <= Bb[2] * 0.5f + 1e-5f) && (fabsf(qy) <= Bb[3] * 0.5f + 1e-5f);
  }
#pragma unroll
  for (int k = 0; k < 4; ++k) {
    float rx = bcx[k] - ax, ry = bcy[k] - ay;
    float qx =  rx * cA + ry * sA, qy = -rx * sA + ry * cA;
    px[20 + k] = bcx[k]; py[20 + k] = bcy[k];
    act[20 + k] = (fabsf(qx) <= Ab[2] * 0.5f + 1e-5f) && (fabsf(qy) <= Ab[3] * 0.5f + 1e-5f);
  }
  int cnt = 0; float sx = 0.f, sy = 0.f;
#pragma unroll
  for (int k = 0; k < 24; ++k)
    if (act[k]) { cnt++; sx += px[k]; sy += py[k]; }
  float fc = (float)(cnt > 1 ? cnt : 1);
  float cx0 = sx / fc, cy0 = sy / fc;
  ull key[24];
#pragma unroll
  for (int k = 0; k < 24; ++k) {
    float ang = atan2f(py[k] - cy0, px[k] - cx0);
    key[k] = act[k] ? ((((ull)mono_f32(ang)) << 5) | (ull)k) : ~0ull;
  }
  ull kmin = ~0ull; float fx = 0.f, fy = 0.f;
#pragma unroll
  for (int k = 0; k < 24; ++k) {
    bool lt = key[k] < kmin;
    kmin = lt ? key[k] : kmin;
    fx = lt ? px[k] : fx;
    fy = lt ? py[k] : fy;
  }
  float ssum = 0.f;
#pragma unroll
  for (int k = 0; k < 24; ++k) {
    ull myk = key[k];
    ull best = ~0ull; float nx = fx, ny = fy;   // default: wrap to first
#pragma unroll
    for (int j = 0; j < 24; ++j) {
      bool c = (key[j] > myk) && (key[j] < best);
      best = c ? key[j] : best;
      nx = c ? px[j] : nx;
      ny = c ? py[j] : ny;
    }
    float contrib = px[k] * ny - py[k] * nx;
    ssum += (myk != ~0ull) ? contrib : 0.f;
  }
  float inter = 0.5f * fabsf(ssum);
  float uni = aA + aB - inter;
  return inter / fmaxf(uni, 1e-6f) > NMS_TH;
}

__device__ __forceinline__ int popbelow(const unsigned* rowbm, int i) {
  int s = 0, w = i >> 5;
  for (int k = 0; k < w; ++k) s += __popc(rowbm[k]);
  s += __popc(rowbm[w] & ((1u << (i & 31)) - 1u));
  return s;
}

// =====================================================================
// K3: cheap sweep -> dense exact IoU -> hit segment; LAST block per batch
//     runs the NMS + compact + gather epilogue (ticket pattern).
// grid = B*64, **512 thr** (2 waves/SIMD for latency hiding).
// Block handles rows i == blk (mod 64).
// =====================================================================
__global__ __launch_bounds__(512) void k_pairsfin(
    const float4* __restrict__ pinfoG, const float* __restrict__ binfo,
    const float* __restrict__ box, const float* __restrict__ cls,
    const int* __restrict__ topi,
    unsigned* __restrict__ hitseg, unsigned* __restrict__ hitcnt,
    unsigned* __restrict__ done, float* __restrict__ out, int B) {
  __shared__ float4 pin[NPRE];         // 16 KB; epilogue aliases -> maskL
  __shared__ unsigned candL[CANDL];    // 8 KB;  epilogue aliases -> rlist
  __shared__ unsigned cntC, cntH;
  __shared__ int amLast;
  const int b = blockIdx.x >> 6, blk = blockIdx.x & 63;
  const int t = threadIdx.x;
  const int lane = t & 63, wv = t >> 6;   // wv in [0,8)
#pragma unroll
  for (int k = 0; k < 2; ++k) pin[k * 512 + t] = pinfoG[(size_t)b * NPRE + k * 512 + t];
  if (t == 0) { cntC = 0u; cntH = 0u; }
  __syncthreads();

  const float* bi = binfo + (size_t)b * NPRE * 16;
  unsigned sbase = ((unsigned)b * 64 + (unsigned)blk) * SEGCAP;
  for (int iter = 0; iter < 32; ++iter) {
    int task = iter * 8 + wv;          // 256 wave-tasks: 16 rows x 16 words
    int q = task >> 4, w = task & 15;
    int i = q * 64 + blk;
    if (w * 64 + 63 <= i) continue;    // wave-uniform
    int j = w * 64 + lane;
    float4 pi = pin[i];
    float4 pj = pin[j];
    bool cnd = false;
    if (j > i) {
      float ddx = pi.x - pj.x, ddy = pi.y - pj.y;
      float rr = pi.z + pj.z + 1e-3f;
      if (ddx * ddx + ddy * ddy <= rr * rr) {            // not provably disjoint
        float mn = fminf(pi.w, pj.w), mx = fmaxf(pi.w, pj.w);
        if (mn > NMS_TH * mx) cnd = true;                // not provably iou<=0.8
      }
    }
    ull bal = __ballot(cnd);
    if (!bal) continue;
    unsigned base = 0;
    if (lane == 0) base = atomicAdd(&cntC, (unsigned)__popcll(bal));
    base = (unsigned)__shfl((int)base, 0, 64);
    if (cnd) {
      unsigned off = base + (unsigned)__popcll(bal & ((1ull << lane) - 1ull));
      unsigned pk = ((unsigned)i << 10) | (unsigned)j;
      if (off < CANDL) candL[off] = pk;
      else {                           // LDS overflow: inline eval (rare-correct)
        if (iou_exact_gt(bi + (size_t)i * 16, bi + (size_t)j * 16)) {
          unsigned h = atomicAdd(&cntH, 1u);
          hitseg[sbase + h] = pk;      // h < SEGCAP by construction (<=16368)
        }
      }
    }
  }
  __syncthreads();

  // dense exact IoU over this block's compacted candidates (8 waves)
  unsigned C = cntC; if (C > CANDL) C = CANDL;
  for (unsigned e = (unsigned)t; e < C; e += 512) {
    unsigned pk = candL[e];
    unsigned i = pk >> 10, j = pk & 1023u;
    if (iou_exact_gt(bi + (size_t)i * 16, bi + (size_t)j * 16)) {
      unsigned h = atomicAdd(&cntH, 1u);
      hitseg[sbase + h] = pk;
    }
  }
  __syncthreads();
  if (t == 0) {
    hitcnt[b * 64 + blk] = (cntH < (unsigned)SEGCAP) ? cntH : (unsigned)SEGCAP;
    __threadfence();                   // release: hitseg/hitcnt device-visible
    unsigned old = atomicAdd(&done[b], 1u);
    amLast = (old == 63u) ? 1 : 0;
  }
  __syncthreads();
  if (!amLast) return;
  __threadfence();                     // acquire on the last block

  // ============ epilogue (R10 k_fin 512-thr shape, verified) ============
  unsigned* maskL = (unsigned*)pin;    // 16 KB: 128 slots x 1024 bits
  unsigned* rlist = candL;             // 4 KB of candL: slot -> row
  __shared__ unsigned segoff[65];
  __shared__ unsigned scnt[64];
  __shared__ unsigned rowbm[32];
  __shared__ ull remv_sh[16];
  __shared__ unsigned smallu[8];
  __shared__ unsigned rn_sh;

  for (int k = t; k < 128 * 32; k += 512) maskL[k] = 0u;
  if (t < 32) rowbm[t] = 0u;
  if (t < 64) scnt[t] = hitcnt[b * 64 + t];   // parallel load
  __syncthreads();
  if (t == 0) {
    unsigned o = 0;
    for (int s = 0; s < 64; ++s) {
      segoff[s] = o;
      unsigned c = scnt[s];
      o += (c < (unsigned)SEGCAP) ? c : (unsigned)SEGCAP;
    }
    segoff[64] = o;
  }
  __syncthreads();
  unsigned H = segoff[64];

  // pass 1: row bitmap
  for (unsigned e = (unsigned)t; e < H; e += 512) {
    int lo = 0, hi = 63;
    while (lo < hi) { int mid = (lo + hi + 1) >> 1; if (segoff[mid] <= e) lo = mid; else hi = mid - 1; }
    unsigned pk = hitseg[((size_t)(b * 64 + lo)) * SEGCAP + (e - segoff[lo])];
    atomicOr(&rowbm[(pk >> 10) >> 5], 1u << ((pk >> 10) & 31));
  }
  __syncthreads();
  for (int row = t; row < NPRE; row += 512) {
    if ((rowbm[row >> 5] >> (row & 31)) & 1u)
      rlist[popbelow(rowbm, row)] = (unsigned)row;
  }
  if (t == 0) {
    unsigned s = 0;
    for (int w = 0; w < 32; ++w) s += (unsigned)__popc(rowbm[w]);
    rn_sh = s;
  }
  __syncthreads();
  // pass 2: slot masks
  for (unsigned e = (unsigned)t; e < H; e += 512) {
    int lo = 0, hi = 63;
    while (lo < hi) { int mid = (lo + hi + 1) >> 1; if (segoff[mid] <= e) lo = mid; else hi = mid - 1; }
    unsigned pk = hitseg[((size_t)(b * 64 + lo)) * SEGCAP + (e - segoff[lo])];
    unsigned i = pk >> 10, j = pk & 1023u;
    int slot = popbelow(rowbm, (int)i);
    if (slot < 128) atomicOr(&maskL[slot * 32 + (j >> 5)], 1u << (j & 31));
  }
  __syncthreads();

  // wave-0 greedy walk at LDS speed
  if (wv == 0) {
    ull remv = 0;                        // lane w<16 holds remv word w
    unsigned rn = rn_sh;
    for (unsigned s = 0; s < rn; ++s) {
      unsigned row = rlist[s];
      ull m = 0;
      if (s < 128) {
        if (lane < 16)
          m = (ull)maskL[s * 32 + lane * 2] | ((ull)maskL[s * 32 + lane * 2 + 1] << 32);
      } else {                           // slow-correct overflow: rescan hits
        for (unsigned e = 0; e < H; ++e) {
          int lo = 0, hi = 63;
          while (lo < hi) { int mid = (lo + hi + 1) >> 1; if (segoff[mid] <= e) lo = mid; else hi = mid - 1; }
          unsigned pk = hitseg[((size_t)(b * 64 + lo)) * SEGCAP + (e - segoff[lo])];
          if ((pk >> 10) == row) {
            unsigned j = pk & 1023u;
            if (lane == (int)(j >> 6)) m |= 1ull << (j & 63);
          }
        }
      }
      ull rw = __shfl(remv, (int)(row >> 6), 64);
      if (!((rw >> (row & 63)) & 1ULL)) remv |= m;
    }
    if (lane < 16) remv_sh[lane] = remv;
  }
  __syncthreads();

  // compact + gather (512 thr x 2 slots)
  int p0 = t * 2;
  ull rw = remv_sh[p0 >> 6];
  int a0 = ((rw >> (p0 & 63)) & 1ULL) ? 0 : 1;
  int a1 = ((rw >> ((p0 + 1) & 63)) & 1ULL) ? 0 : 1;
  int myc = a0 + a1;
  int v = myc;
#pragma unroll
  for (int off = 1; off < 64; off <<= 1) {
    int t2 = __shfl_up(v, off, 64);
    if (lane >= off) v += t2;
  }
  if (lane == 63) smallu[wv] = (unsigned)v;
  __syncthreads();
  int pre = 0;
  for (int w2 = 0; w2 < wv; ++w2) pre += (int)smallu[w2];
  int total = 0;
  for (int w2 = 0; w2 < 8; ++w2) total += (int)smallu[w2];
  int s = pre + v - myc;

  float* rois   = out;
  float* scores = out + (size_t)B * NPOST * 7;
  float* labels = scores + (size_t)B * NPOST;
  float* logits = labels + (size_t)B * NPOST;
  int aa[2] = {a0, a1};
#pragma unroll
  for (int k = 0; k < 2; ++k) {
    if (aa[k] && s < NPOST) {
      int orig = topi[b * NPRE + p0 + k];
      const float* bb = box + ((size_t)b * NBOX + orig) * 7;
      float* ro = rois + ((size_t)b * NPOST + s) * 7;
#pragma unroll
      for (int c2 = 0; c2 < 7; ++c2) ro[c2] = bb[c2];
      const float* cc = cls + ((size_t)b * NBOX + orig) * 3;
      float l0 = cc[0], l1 = cc[1], l2 = cc[2];
      float m = fmaxf(l0, fmaxf(l1, l2));
      int lab = (l0 == m) ? 0 : ((l1 == m) ? 1 : 2);   // argmax: first max
      scores[b * NPOST + s] = m;
      labels[b * NPOST + s] = (float)(lab + 1);
      float* lg = logits + ((size_t)b * NPOST + s) * 3;
      lg[0] = l0; lg[1] = l1; lg[2] = l2;
    }
    s += aa[k];
  }
  if (t < NPOST && t >= total) {         // invalid slots: zeros, label 1
    float* ro = rois + ((size_t)b * NPOST + t) * 7;
#pragma unroll
    for (int c2 = 0; c2 < 7; ++c2) ro[c2] = 0.f;
    scores[b * NPOST + t] = 0.f;
    labels[b * NPOST + t] = 1.f;
    float* lg = logits + ((size_t)b * NPOST + t) * 3;
    lg[0] = 0.f; lg[1] = 0.f; lg[2] = 0.f;
  }
}

extern "C" void kernel_launch(void* const* d_in, const int* in_sizes, int n_in,
                              void* d_out, int out_size, void* d_ws, size_t ws_size,
                              hipStream_t stream) {
  const float* box = (const float*)d_in[0];
  const float* cls = (const float*)d_in[1];
  float* out = (float*)d_out;
  int B = in_sizes[0] / (NBOX * 7);    // == 2

  char* w = (char*)d_ws;
  size_t off = 0;
  ull* cand        = (ull*)(w + off);      off += (size_t)B * 8 * 2048 * sizeof(ull);
  unsigned* candCt = (unsigned*)(w + off); off += (size_t)B * 8 * sizeof(unsigned);
  int* topi        = (int*)(w + off);      off += (size_t)B * NPRE * sizeof(int);
  unsigned* hitcnt = (unsigned*)(w + off); off += (size_t)B * 64 * sizeof(unsigned);
  unsigned* done   = (unsigned*)(w + off); off += 64 * sizeof(unsigned);
  off = (off + 63) & ~(size_t)63;
  float* binfo     = (float*)(w + off);    off += (size_t)B * NPRE * 16 * sizeof(float);
  float4* pinfoG   = (float4*)(w + off);   off += (size_t)B * NPRE * sizeof(float4);
  unsigned* hitseg = (unsigned*)(w + off); off += (size_t)B * 64 * SEGCAP * sizeof(unsigned);
  (void)off; (void)ws_size; (void)out_size; (void)n_in;

  hipLaunchKernelGGL(k_sel,      dim3(B * 8),  dim3(256), 0, stream, cls, cand, candCt, done);
  hipLaunchKernelGGL(k_rank,     dim3(B * 8),  dim3(256), 0, stream, box, cand, candCt, topi, binfo, pinfoG);
  hipLaunchKernelGGL(k_pairsfin, dim3(B * 64), dim3(512), 0, stream, pinfoG, binfo, box, cls, topi,
                     hitseg, hitcnt, done, out, B);
}